// Round 6
// baseline (203.639 us; speedup 1.0000x reference)
//
#include <hip/hip_runtime.h>

// GCN on MI355X — round 18: revert k_fine to r16 two-pass logic (r17 single
// pass was neutral->worse: kernel is latency-bound, not work-bound), and split
// each bucket across TWO 128-node half-blocks (782 blocks x 256 thr, ~3
// blocks/CU vs 1.5). Mechanism: multi-phase barrier-separated blocks need
// other resident blocks to hide per-phase global/atomic latency. Half h reads
// the full bucket (stg read x2, +2us BW) but counts/scans/scatters only its
// 128 nodes; h=1 derives its intra-bucket offset by register-reducing the
// low-half entry count (no atomics). k_init/k_part/k_q/k_agg/k_mlp identical
// to r16 (195.6us).

#define HD 128
#define HD2 256
#define BSHIFT 8             // 256 nodes per bucket -> 391 buckets
#define BNODES 256
#define SRCBITS 17           // N=100000 < 2^17
#define EPB 4096             // edges per k_part block

typedef __attribute__((ext_vector_type(8))) short bf8_t;   // 8 x bf16 (4 VGPR)
typedef __attribute__((ext_vector_type(4))) float f32x4;

static inline size_t align256(size_t x) { return (x + 255) & ~(size_t)255; }

__device__ inline ushort f2bf(float f) {            // RNE f32 -> bf16
    uint u = __float_as_uint(f);
    uint r = u + 0x7fffu + ((u >> 16) & 1u);
    return (ushort)(r >> 16);
}
__device__ inline uint packbf(float a, float b) {
    return (uint)f2bf(a) | ((uint)f2bf(b) << 16);
}

// prepB (weights -> bf16 chunk layout) + zero bfill. 128 blocks x 256.
__global__ void k_init(const float* __restrict__ W2, const float* __restrict__ Wl1,
                       ushort* __restrict__ Bt1, ushort* __restrict__ Bt2,
                       int* __restrict__ bfill) {
    int o = blockIdx.x * blockDim.x + threadIdx.x;
    if (o < 512) bfill[o] = 0;
    if (o >= 32768) return;
    {   // Bt1: K=128, NCOLS=256: Bt[(k>>3)*256*8 + n*8 + (k&7)]
        int k0 = o & 7, n = (o >> 3) & 255, k8 = o >> 11;
        Bt1[o] = f2bf(W2[(size_t)(k8 * 8 + k0) * 256 + n]);
    }
    {   // Bt2: K=256, NCOLS=128
        int k0 = o & 7, n = (o >> 3) & 127, k8 = o >> 10;
        Bt2[o] = f2bf(Wl1[(size_t)(k8 * 8 + k0) * 128 + n]);
    }
}

// Phase 1 v2: stream 4096 edges/block, partition into 391 dst-buckets with
// block-local grouping so global stores are contiguous runs (~84B) per bucket.
__global__ __launch_bounds__(256) void k_part(const int* __restrict__ ei,
                                              const float* __restrict__ ew,
                                              int* __restrict__ bfill,
                                              uint2* __restrict__ stg,
                                              int E, int nbuck, int cap) {
    __shared__ int lcnt[4][512];       // per-wave bucket counts -> tot in [0]
    __shared__ int lbase[4][512];      // per-wave exclusive prefix per bucket
    __shared__ int lpre[512];          // block-local exclusive bucket start
    __shared__ int delta[512];         // global_addr = delta[bkt] + loc
    __shared__ uint2 sstage[EPB];      // 32 KB staged (pack, w)
    __shared__ uint  ga[EPB];          // 16 KB precomputed global slots
    __shared__ int wscan[8];
    __shared__ int nvs;
    int tid = threadIdx.x;
    int wvid = tid >> 6, lane = tid & 63;
    for (int i = tid; i < 512; i += 256) {
        lcnt[0][i] = 0; lcnt[1][i] = 0; lcnt[2][i] = 0; lcnt[3][i] = 0;
    }
    __syncthreads();
    bool is64 = (ei[1] == 0) && (ei[3] == 0) && (ei[5] == 0) && (ei[7] == 0);
    int e0 = blockIdx.x * EPB;
    uint pack[16]; uint wb[16]; short bkt[16]; short rank[16];
    for (int u = 0; u < 16; u++) {
        int e = e0 + u * 256 + tid;
        bkt[u] = -1;
        if (e < E) {
            int s, d;
            if (is64) { s = ei[2 * e]; d = ei[2 * (E + e)]; }
            else      { s = ei[e];     d = ei[E + e]; }
            bkt[u] = (short)(d >> BSHIFT);
            pack[u] = ((uint)(d & (BNODES - 1)) << SRCBITS) | (uint)s;
            wb[u] = __float_as_uint(ew[e]);
            rank[u] = (short)atomicAdd(&lcnt[wvid][bkt[u]], 1);  // <=1024, fits
        }
    }
    __syncthreads();
    for (int i = tid; i < 512; i += 256) {
        int t0 = lcnt[0][i], t1 = lcnt[1][i], t2 = lcnt[2][i], t3 = lcnt[3][i];
        lbase[0][i] = 0; lbase[1][i] = t0;
        lbase[2][i] = t0 + t1; lbase[3][i] = t0 + t1 + t2;
        lcnt[0][i] = t0 + t1 + t2 + t3;            // tot
    }
    __syncthreads();
    // inclusive scan of tot over 512 buckets: 8 wave-segments of 64
    int inc[2];
    for (int r = 0; r < 2; r++) {
        int v = lcnt[0][r * 256 + tid];
        for (int off = 1; off < 64; off <<= 1) {
            int u = __shfl_up(v, off);
            if (lane >= off) v += u;
        }
        inc[r] = v;
        if (lane == 63) wscan[r * 4 + wvid] = v;
    }
    __syncthreads();
    if (tid == 0) {
        int run = 0;
        for (int s2 = 0; s2 < 8; s2++) { int t = wscan[s2]; wscan[s2] = run; run += t; }
        nvs = run;
    }
    __syncthreads();
    for (int r = 0; r < 2; r++) {
        int i = r * 256 + tid;
        int tot = lcnt[0][i];
        int excl = inc[r] - tot + wscan[r * 4 + wvid];
        int gb = 0;
        if (tot && i < nbuck) gb = atomicAdd(&bfill[i], tot);
        lpre[i] = excl;
        delta[i] = i * cap + gb - excl;            // < 2^31, window line-aligned
    }
    __syncthreads();
    for (int u = 0; u < 16; u++)
        if (bkt[u] >= 0) {
            int b = bkt[u];
            int loc = lpre[b] + lbase[wvid][b] + rank[u];
            sstage[loc] = make_uint2(pack[u], wb[u]);
            ga[loc] = (uint)(delta[b] + loc);
        }
    __syncthreads();
    int nv = nvs;
    for (int ch = 0; ch < 16; ch++) {              // lanes adjacent -> runs
        int loc = ch * 256 + tid;
        if (loc < nv) stg[ga[loc]] = sstage[loc];
    }
}

// Phase 2 v3: TWO 256-thread blocks per bucket; block (B,h) owns the 128
// nodes [B*256 + h*128, +128). Reads the whole bucket, counts/scans/scatters
// only its half. h=1's intra-bucket base = register-reduced low-half count.
__global__ __launch_bounds__(256) void k_fine(const uint2* __restrict__ stg,
                                              const int* __restrict__ bfill,
                                              const float* __restrict__ x,
                                              float* __restrict__ dis,
                                              float* __restrict__ p,
                                              int* __restrict__ rowptr,
                                              int2* __restrict__ cv,
                                              int cap, int N, int E, int nbuck) {
    __shared__ int cnt_l[128];
    __shared__ int base_l[128];
    __shared__ float degf[128];
    __shared__ int wsum[4];
    __shared__ int wlow[4];
    __shared__ int ws2[2];
    int B = blockIdx.x >> 1, h = blockIdx.x & 1;
    int tid = threadIdx.x;
    int lane = tid & 63, wvid = tid >> 6;
    // cvbase(B) = sum_{i<B} bfill[i]  (B < 512; 256 threads read <=2 each)
    int a = (tid < B) ? bfill[tid] : 0;
    if (tid + 256 < B) a += bfill[tid + 256];
    for (int off = 32; off > 0; off >>= 1) a += __shfl_xor(a, off);
    if (lane == 0) wsum[wvid] = a;
    if (tid < 128) { cnt_l[tid] = 0; degf[tid] = 1.0f; }
    __syncthreads();
    int cb = wsum[0] + wsum[1] + wsum[2] + wsum[3];
    int n = bfill[B];
    if (B == nbuck - 1 && h == 0 && tid == 0) rowptr[N] = E;
    const uint2* s = stg + (size_t)B * cap;
    // pass 1: histogram + degf for own half; register-count low-half entries
    int mylow = 0;
    for (int i = tid; i < n; i += 256) {
        uint2 r = s[i];
        int dl = r.x >> SRCBITS;
        mylow += (dl < 128) ? 1 : 0;
        if ((dl >> 7) == h) {
            atomicAdd(&cnt_l[dl & 127], 1);
            atomicAdd(&degf[dl & 127], __uint_as_float(r.y));
        }
    }
    for (int off = 32; off > 0; off >>= 1) mylow += __shfl_xor(mylow, off);
    if (lane == 0) wlow[wvid] = mylow;
    __syncthreads();
    int lowsum = h ? (wlow[0] + wlow[1] + wlow[2] + wlow[3]) : 0;
    // scan 128 counters (waves 0-1), reset fill counters
    int c = (tid < 128) ? cnt_l[tid] : 0;
    int v = c;
    for (int off = 1; off < 64; off <<= 1) {
        int u = __shfl_up(v, off);
        if (lane >= off) v += u;
    }
    if (wvid < 2 && lane == 63) ws2[wvid] = v;
    __syncthreads();
    if (tid < 128) {
        int wpre = (wvid == 1) ? ws2[0] : 0;
        base_l[tid] = v + wpre - c;
        cnt_l[tid] = 0;                  // reuse as fill counter
    }
    __syncthreads();
    // epilogue first (independent; overlaps scatter stores)
    int gid = (B << BSHIFT) + (h << 7) + tid;
    if (tid < 128 && gid < N) {
        rowptr[gid] = cb + lowsum + base_l[tid];
        float r = rsqrtf(degf[tid]);
        dis[gid] = r;
        p[gid] = r * x[gid];
    }
    // pass 2: ranked scatter of own-half entries
    for (int i = tid; i < n; i += 256) {
        uint2 r = s[i];
        int dl = r.x >> SRCBITS;
        if ((dl >> 7) == h) {
            int src = (int)(r.x & ((1u << SRCBITS) - 1));
            int pos = cb + lowsum + base_l[dl & 127] + atomicAdd(&cnt_l[dl & 127], 1);
            cv[pos] = make_int2(src, (int)r.y);
        }
    }
}

// Quarter-wave per node: q = sum(val*p[col]); t = dis*(q+p); tp = (t, dis).
__global__ __launch_bounds__(256) void k_q(const int* __restrict__ rowptr,
                                           const int2* __restrict__ cv,
                                           const float* __restrict__ dis,
                                           const float* __restrict__ p,
                                           float2* __restrict__ tp, int N) {
    int gid = blockIdx.x * blockDim.x + threadIdx.x;
    int wid = gid >> 4;
    int sl = threadIdx.x & 15;
    if (wid >= N) return;
    int beg = rowptr[wid], end = rowptr[wid + 1];
    float s = 0.0f;
    for (int i = beg + sl; i < end; i += 16) {
        int2 pr = cv[i];
        s += __int_as_float(pr.y) * p[pr.x];
    }
    s += __shfl_xor(s, 1);
    s += __shfl_xor(s, 2);
    s += __shfl_xor(s, 4);
    s += __shfl_xor(s, 8);
    if (sl == 0) {
        float r = dis[wid];
        tp[wid] = make_float2(r * (s + p[wid]), r);
    }
}

// Half-wave per node: lanes 0-31 -> node A, 32-63 -> node B; 4 features/lane.
__global__ __launch_bounds__(256) void k_agg(const int* __restrict__ rowptr,
                                             const int2* __restrict__ cv,
                                             const float2* __restrict__ tp,
                                             const float* __restrict__ W1,
                                             const float* __restrict__ b1,
                                             uint* __restrict__ z, int N) {
    __shared__ float2 eb[4][64];       // 2 KB: per-wave, 32 slots per half
    int tid = threadIdx.x;
    int wvid = tid >> 6, lane = tid & 63;
    int half = lane >> 5, hl = lane & 31;
    int node = ((blockIdx.x * 256 + tid) >> 6) * 2 + half;
    bool valid = node < N;
    float4 w1 = valid ? *(const float4*)(W1 + hl * 4) : make_float4(0, 0, 0, 0);
    float4 bb = valid ? *(const float4*)(b1 + hl * 4) : make_float4(0, 0, 0, 0);
    int beg = 0, end = 0;
    if (valid) { beg = rowptr[node]; end = rowptr[node + 1]; }
    int nb = (end - beg + 31) >> 5;
    nb = max(nb, __shfl_xor(nb, 32));            // uniform across the wave pair
    float4 aA = make_float4(0, 0, 0, 0), aB = make_float4(0, 0, 0, 0);
    const float4* ebp = (const float4*)&eb[wvid][half * 32];
    for (int bt = 0; bt < nb; bt++) {
        int eidx = beg + bt * 32 + hl;
        float wd = 0.0f, tt = 0.0f;
        if (eidx < end) {
            int2 pr = cv[eidx];
            float2 tps = tp[pr.x];               // 8B gather, L2-resident
            wd = __int_as_float(pr.y) * tps.y;   // w_e * dis_src
            tt = tps.x;                          // t_src
        }
        eb[wvid][lane] = make_float2(wd, tt);
        int m = min(32, end - (beg + bt * 32)); if (m < 0) m = 0;
        int hm = (m + 1) >> 1;
        hm = max(hm, __shfl_xor(hm, 32));
        int u = 0;
        for (; u + 2 <= hm; u += 2) {
            float4 e2 = ebp[u];
            float4 e3 = ebp[u + 1];
            aA.x = fmaf(e2.x, fmaxf(fmaf(e2.y, w1.x, bb.x), 0.f), aA.x);
            aA.y = fmaf(e2.x, fmaxf(fmaf(e2.y, w1.y, bb.y), 0.f), aA.y);
            aA.z = fmaf(e2.x, fmaxf(fmaf(e2.y, w1.z, bb.z), 0.f), aA.z);
            aA.w = fmaf(e2.x, fmaxf(fmaf(e2.y, w1.w, bb.w), 0.f), aA.w);
            aA.x = fmaf(e2.z, fmaxf(fmaf(e2.w, w1.x, bb.x), 0.f), aA.x);
            aA.y = fmaf(e2.z, fmaxf(fmaf(e2.w, w1.y, bb.y), 0.f), aA.y);
            aA.z = fmaf(e2.z, fmaxf(fmaf(e2.w, w1.z, bb.z), 0.f), aA.z);
            aA.w = fmaf(e2.z, fmaxf(fmaf(e2.w, w1.w, bb.w), 0.f), aA.w);
            aB.x = fmaf(e3.x, fmaxf(fmaf(e3.y, w1.x, bb.x), 0.f), aB.x);
            aB.y = fmaf(e3.x, fmaxf(fmaf(e3.y, w1.y, bb.y), 0.f), aB.y);
            aB.z = fmaf(e3.x, fmaxf(fmaf(e3.y, w1.z, bb.z), 0.f), aB.z);
            aB.w = fmaf(e3.x, fmaxf(fmaf(e3.y, w1.w, bb.w), 0.f), aB.w);
            aB.x = fmaf(e3.z, fmaxf(fmaf(e3.w, w1.x, bb.x), 0.f), aB.x);
            aB.y = fmaf(e3.z, fmaxf(fmaf(e3.w, w1.y, bb.y), 0.f), aB.y);
            aB.z = fmaf(e3.z, fmaxf(fmaf(e3.w, w1.z, bb.z), 0.f), aB.z);
            aB.w = fmaf(e3.z, fmaxf(fmaf(e3.w, w1.w, bb.w), 0.f), aB.w);
        }
        if (u < hm) {
            float4 e2 = ebp[u];
            aA.x = fmaf(e2.x, fmaxf(fmaf(e2.y, w1.x, bb.x), 0.f), aA.x);
            aA.y = fmaf(e2.x, fmaxf(fmaf(e2.y, w1.y, bb.y), 0.f), aA.y);
            aA.z = fmaf(e2.x, fmaxf(fmaf(e2.y, w1.z, bb.z), 0.f), aA.z);
            aA.w = fmaf(e2.x, fmaxf(fmaf(e2.y, w1.w, bb.w), 0.f), aA.w);
            aA.x = fmaf(e2.z, fmaxf(fmaf(e2.w, w1.x, bb.x), 0.f), aA.x);
            aA.y = fmaf(e2.z, fmaxf(fmaf(e2.w, w1.y, bb.y), 0.f), aA.y);
            aA.z = fmaf(e2.z, fmaxf(fmaf(e2.w, w1.z, bb.z), 0.f), aA.z);
            aA.w = fmaf(e2.z, fmaxf(fmaf(e2.w, w1.w, bb.w), 0.f), aA.w);
        }
    }
    if (!valid) return;
    float2 tpd = tp[node];
    float rd = tpd.y;
    float o0 = rd * (aA.x + aB.x + rd * fmaxf(fmaf(tpd.x, w1.x, bb.x), 0.f));
    float o1 = rd * (aA.y + aB.y + rd * fmaxf(fmaf(tpd.x, w1.y, bb.y), 0.f));
    float o2 = rd * (aA.z + aB.z + rd * fmaxf(fmaf(tpd.x, w1.z, bb.z), 0.f));
    float o3 = rd * (aA.w + aB.w + rd * fmaxf(fmaf(tpd.x, w1.w, bb.w), 0.f));
    ((uint2*)(z + (size_t)node * 64))[hl] = make_uint2(packbf(o0, o1), packbf(o2, o3));
}

// Fused MLP: out[i] = relu(relu(z[i]@W2+b2)@Wl1+bl1).wl2 + bl2.
__global__ __launch_bounds__(256) void k_mlp(const ushort* __restrict__ A,    // z bf16 [N][128]
                                             const ushort* __restrict__ Bt1,  // [16][256][8]
                                             const ushort* __restrict__ Bt2,  // [32][128][8]
                                             const float* __restrict__ b2,
                                             const float* __restrict__ bl1,
                                             const float* __restrict__ wl2,
                                             const float* __restrict__ bl2,
                                             float* __restrict__ out, int M) {
    __shared__ ushort st[4][32][40];   // per-wave C->A staging; 80B row stride
    int tid = threadIdx.x;
    int wv = tid >> 6, lane = tid & 63;
    int l15 = lane & 15, quad = lane >> 4;
    int row0 = blockIdx.x * 128 + wv * 32;
    int r0 = row0 + l15;      r0 = r0 < M ? r0 : M - 1;   // clamp; stores guarded
    int r1 = row0 + 16 + l15; r1 = r1 < M ? r1 : M - 1;

    bf8_t a1[2][4];                       // all A1 frags resident (32 VGPR)
    for (int kc = 0; kc < 4; kc++) {
        a1[0][kc] = *(const bf8_t*)(A + (size_t)r0 * 128 + kc * 32 + quad * 8);
        a1[1][kc] = *(const bf8_t*)(A + (size_t)r1 * 128 + kc * 32 + quad * 8);
    }
    f32x4 acc2[2][8];
    for (int i = 0; i < 2; i++)
        for (int j = 0; j < 8; j++) acc2[i][j] = (f32x4){0.f, 0.f, 0.f, 0.f};

    for (int c = 0; c < 8; c++) {         // 32-col chunk of h2 == 32-k of GEMM2
        f32x4 acc1[2][2];
        for (int i = 0; i < 2; i++)
            for (int j = 0; j < 2; j++) acc1[i][j] = (f32x4){0.f, 0.f, 0.f, 0.f};
        for (int kc = 0; kc < 4; kc++)
            for (int nt = 0; nt < 2; nt++) {
                bf8_t b = *(const bf8_t*)(Bt1 +
                    ((size_t)(kc * 4 + quad) * 256 + c * 32 + nt * 16 + l15) * 8);
                acc1[0][nt] = __builtin_amdgcn_mfma_f32_16x16x32_bf16(a1[0][kc], b, acc1[0][nt], 0, 0, 0);
                acc1[1][nt] = __builtin_amdgcn_mfma_f32_16x16x32_bf16(a1[1][kc], b, acc1[1][nt], 0, 0, 0);
            }
        for (int nt = 0; nt < 2; nt++) {
            float bb = b2[c * 32 + nt * 16 + l15];
            for (int mt = 0; mt < 2; mt++)
                for (int rg = 0; rg < 4; rg++)
                    st[wv][mt * 16 + quad * 4 + rg][nt * 16 + l15] =
                        f2bf(fmaxf(acc1[mt][nt][rg] + bb, 0.f));
        }
        bf8_t a2_0 = *(const bf8_t*)&st[wv][l15][quad * 8];
        bf8_t a2_1 = *(const bf8_t*)&st[wv][16 + l15][quad * 8];
        for (int nt2 = 0; nt2 < 8; nt2++) {
            bf8_t b = *(const bf8_t*)(Bt2 +
                ((size_t)(c * 4 + quad) * 128 + nt2 * 16 + l15) * 8);
            acc2[0][nt2] = __builtin_amdgcn_mfma_f32_16x16x32_bf16(a2_0, b, acc2[0][nt2], 0, 0, 0);
            acc2[1][nt2] = __builtin_amdgcn_mfma_f32_16x16x32_bf16(a2_1, b, acc2[1][nt2], 0, 0, 0);
        }
    }
    float rs[2][4] = {};
    for (int nt2 = 0; nt2 < 8; nt2++) {
        int col = nt2 * 16 + l15;
        float bb = bl1[col], ww = wl2[col];
        for (int mt = 0; mt < 2; mt++)
            for (int rg = 0; rg < 4; rg++)
                rs[mt][rg] += fmaxf(acc2[mt][nt2][rg] + bb, 0.f) * ww;
    }
    float base = bl2[0];
    for (int mt = 0; mt < 2; mt++)
        for (int rg = 0; rg < 4; rg++) {
            float s = rs[mt][rg];
            s += __shfl_xor(s, 1);
            s += __shfl_xor(s, 2);
            s += __shfl_xor(s, 4);
            s += __shfl_xor(s, 8);
            int row = row0 + mt * 16 + quad * 4 + rg;
            if (l15 == 0 && row < M) out[row] = s + base;
        }
}

extern "C" void kernel_launch(void* const* d_in, const int* in_sizes, int n_in,
                              void* d_out, int out_size, void* d_ws, size_t ws_size,
                              hipStream_t stream) {
    const float* x   = (const float*)d_in[0];
    const int*   ei  = (const int*)d_in[1];
    const float* ew  = (const float*)d_in[2];
    const float* W1  = (const float*)d_in[3];
    const float* b1  = (const float*)d_in[4];
    const float* W2  = (const float*)d_in[5];
    const float* b2  = (const float*)d_in[6];
    const float* Wl1 = (const float*)d_in[7];
    const float* bl1 = (const float*)d_in[8];
    const float* Wl2 = (const float*)d_in[9];
    const float* bl2 = (const float*)d_in[10];
    float* out = (float*)d_out;
    const int N = in_sizes[0];
    const int E = in_sizes[2];

    const int nbuck = (N + BNODES - 1) >> BSHIFT;             // 391
    const int cap = ((((E / nbuck) * 5) / 4 + 1024) + 7) & ~7; // slack, 64B-aligned

    char* w = (char*)d_ws;
    size_t off = 0;
    auto alloc = [&](size_t bytes) -> void* {
        void* p = w + off;
        off = align256(off + bytes);
        return p;
    };
    uint*   z      = (uint*)alloc((size_t)N * 64 * 4);      // bf16 [N][128]
    float2* tp     = (float2*)alloc((size_t)N * 8);         // (t, dis)
    float*  dis    = (float*)alloc((size_t)N * 4);
    float*  p_     = (float*)alloc((size_t)N * 4);
    int*    rowptr = (int*)alloc((size_t)(N + 1) * 4);
    int2*   cv     = (int2*)alloc((size_t)E * 8);
    uint2*  stg    = (uint2*)alloc((size_t)nbuck * cap * 8);
    int*    bfill  = (int*)alloc(512 * 4);
    ushort* Bt1    = (ushort*)alloc(32768 * 2);
    ushort* Bt2    = (ushort*)alloc(32768 * 2);

    k_init<<<128, 256, 0, stream>>>(W2, Wl1, Bt1, Bt2, bfill);
    k_part<<<(E + EPB - 1) / EPB, 256, 0, stream>>>(ei, ew, bfill, stg, E, nbuck, cap);
    k_fine<<<2 * nbuck, 256, 0, stream>>>(stg, bfill, x, dis, p_, rowptr, cv, cap, N, E, nbuck);
    k_q<<<(N * 16 + 255) / 256, 256, 0, stream>>>(rowptr, cv, dis, p_, tp, N);
    k_agg<<<(N + 7) / 8, 256, 0, stream>>>(rowptr, cv, tp, W1, b1, z, N);
    k_mlp<<<(N + 127) / 128, 256, 0, stream>>>((const ushort*)z, Bt1, Bt2,
                                               b2, bl1, Wl2, bl2, out, N);
}

// Round 7
// 196.650 us; speedup vs baseline: 1.0355x; 1.0355x over previous
//
#include <hip/hip_runtime.h>

// GCN on MI355X — round 19: revert k_fine to r16 two-pass (r18 split cost
// +8us: doubled stg read > occupancy gain; k_fine is structural now).
// k_mlp v2: 16 rows/wave (grid x2 = 1563 blocks, ~6 blocks/CU -> ~2x TLP for
// the latency-bound MFMA->LDS->MFMA chain) + double-buffered st[c&1] to kill
// the WAR serialization between iteration c's a2-reads and c+1's staging
// writes. Same total MFMA work; B-frags re-read 2x (L1-hot).
// r18 counters for k_mlp: 41.8us, MfmaUtil 10.9%, Occ 14% -> latency-bound.

#define HD 128
#define HD2 256
#define BSHIFT 8             // 256 nodes per bucket -> 391 buckets
#define BNODES 256
#define SRCBITS 17           // N=100000 < 2^17
#define EPB 4096             // edges per k_part block

typedef __attribute__((ext_vector_type(8))) short bf8_t;   // 8 x bf16 (4 VGPR)
typedef __attribute__((ext_vector_type(4))) float f32x4;

static inline size_t align256(size_t x) { return (x + 255) & ~(size_t)255; }

__device__ inline ushort f2bf(float f) {            // RNE f32 -> bf16
    uint u = __float_as_uint(f);
    uint r = u + 0x7fffu + ((u >> 16) & 1u);
    return (ushort)(r >> 16);
}
__device__ inline uint packbf(float a, float b) {
    return (uint)f2bf(a) | ((uint)f2bf(b) << 16);
}

// prepB (weights -> bf16 chunk layout) + zero bfill. 128 blocks x 256.
__global__ void k_init(const float* __restrict__ W2, const float* __restrict__ Wl1,
                       ushort* __restrict__ Bt1, ushort* __restrict__ Bt2,
                       int* __restrict__ bfill) {
    int o = blockIdx.x * blockDim.x + threadIdx.x;
    if (o < 512) bfill[o] = 0;
    if (o >= 32768) return;
    {   // Bt1: K=128, NCOLS=256: Bt[(k>>3)*256*8 + n*8 + (k&7)]
        int k0 = o & 7, n = (o >> 3) & 255, k8 = o >> 11;
        Bt1[o] = f2bf(W2[(size_t)(k8 * 8 + k0) * 256 + n]);
    }
    {   // Bt2: K=256, NCOLS=128
        int k0 = o & 7, n = (o >> 3) & 127, k8 = o >> 10;
        Bt2[o] = f2bf(Wl1[(size_t)(k8 * 8 + k0) * 128 + n]);
    }
}

// Phase 1 v2: stream 4096 edges/block, partition into 391 dst-buckets with
// block-local grouping so global stores are contiguous runs (~84B) per bucket.
__global__ __launch_bounds__(256) void k_part(const int* __restrict__ ei,
                                              const float* __restrict__ ew,
                                              int* __restrict__ bfill,
                                              uint2* __restrict__ stg,
                                              int E, int nbuck, int cap) {
    __shared__ int lcnt[4][512];       // per-wave bucket counts -> tot in [0]
    __shared__ int lbase[4][512];      // per-wave exclusive prefix per bucket
    __shared__ int lpre[512];          // block-local exclusive bucket start
    __shared__ int delta[512];         // global_addr = delta[bkt] + loc
    __shared__ uint2 sstage[EPB];      // 32 KB staged (pack, w)
    __shared__ uint  ga[EPB];          // 16 KB precomputed global slots
    __shared__ int wscan[8];
    __shared__ int nvs;
    int tid = threadIdx.x;
    int wvid = tid >> 6, lane = tid & 63;
    for (int i = tid; i < 512; i += 256) {
        lcnt[0][i] = 0; lcnt[1][i] = 0; lcnt[2][i] = 0; lcnt[3][i] = 0;
    }
    __syncthreads();
    bool is64 = (ei[1] == 0) && (ei[3] == 0) && (ei[5] == 0) && (ei[7] == 0);
    int e0 = blockIdx.x * EPB;
    uint pack[16]; uint wb[16]; short bkt[16]; short rank[16];
    for (int u = 0; u < 16; u++) {
        int e = e0 + u * 256 + tid;
        bkt[u] = -1;
        if (e < E) {
            int s, d;
            if (is64) { s = ei[2 * e]; d = ei[2 * (E + e)]; }
            else      { s = ei[e];     d = ei[E + e]; }
            bkt[u] = (short)(d >> BSHIFT);
            pack[u] = ((uint)(d & (BNODES - 1)) << SRCBITS) | (uint)s;
            wb[u] = __float_as_uint(ew[e]);
            rank[u] = (short)atomicAdd(&lcnt[wvid][bkt[u]], 1);  // <=1024, fits
        }
    }
    __syncthreads();
    for (int i = tid; i < 512; i += 256) {
        int t0 = lcnt[0][i], t1 = lcnt[1][i], t2 = lcnt[2][i], t3 = lcnt[3][i];
        lbase[0][i] = 0; lbase[1][i] = t0;
        lbase[2][i] = t0 + t1; lbase[3][i] = t0 + t1 + t2;
        lcnt[0][i] = t0 + t1 + t2 + t3;            // tot
    }
    __syncthreads();
    // inclusive scan of tot over 512 buckets: 8 wave-segments of 64
    int inc[2];
    for (int r = 0; r < 2; r++) {
        int v = lcnt[0][r * 256 + tid];
        for (int off = 1; off < 64; off <<= 1) {
            int u = __shfl_up(v, off);
            if (lane >= off) v += u;
        }
        inc[r] = v;
        if (lane == 63) wscan[r * 4 + wvid] = v;
    }
    __syncthreads();
    if (tid == 0) {
        int run = 0;
        for (int s2 = 0; s2 < 8; s2++) { int t = wscan[s2]; wscan[s2] = run; run += t; }
        nvs = run;
    }
    __syncthreads();
    for (int r = 0; r < 2; r++) {
        int i = r * 256 + tid;
        int tot = lcnt[0][i];
        int excl = inc[r] - tot + wscan[r * 4 + wvid];
        int gb = 0;
        if (tot && i < nbuck) gb = atomicAdd(&bfill[i], tot);
        lpre[i] = excl;
        delta[i] = i * cap + gb - excl;            // < 2^31, window line-aligned
    }
    __syncthreads();
    for (int u = 0; u < 16; u++)
        if (bkt[u] >= 0) {
            int b = bkt[u];
            int loc = lpre[b] + lbase[wvid][b] + rank[u];
            sstage[loc] = make_uint2(pack[u], wb[u]);
            ga[loc] = (uint)(delta[b] + loc);
        }
    __syncthreads();
    int nv = nvs;
    for (int ch = 0; ch < 16; ch++) {              // lanes adjacent -> runs
        int loc = ch * 256 + tid;
        if (loc < nv) stg[ga[loc]] = sstage[loc];
    }
}

// Phase 2 (r16 version): one 512-thread block per 256-node bucket. Inline
// cvbase reduction -> LDS count -> scan -> ranked scatter. Fused rowptr/dis/p.
__global__ __launch_bounds__(512) void k_fine(const uint2* __restrict__ stg,
                                              const int* __restrict__ bfill,
                                              const float* __restrict__ x,
                                              float* __restrict__ dis,
                                              float* __restrict__ p,
                                              int* __restrict__ rowptr,
                                              int2* __restrict__ cv,
                                              int cap, int N, int E, int nbuck) {
    __shared__ int cnt_l[BNODES];
    __shared__ int base_l[BNODES];
    __shared__ float degf[BNODES];
    __shared__ int wsum[8];
    int b = blockIdx.x, tid = threadIdx.x;
    int lane = tid & 63, wvid = tid >> 6;
    // cvbase[b] = sum_{i<b} bfill[i] via masked block reduction
    int a = (tid < b && tid < nbuck) ? bfill[tid] : 0;   // nbuck <= 512
    for (int off = 32; off > 0; off >>= 1) a += __shfl_xor(a, off);
    if (lane == 0) wsum[wvid] = a;
    __syncthreads();
    int cb = wsum[0] + wsum[1] + wsum[2] + wsum[3] +
             wsum[4] + wsum[5] + wsum[6] + wsum[7];
    int n = bfill[b];
    if (b == nbuck - 1 && tid == 0) rowptr[N] = E;
    const uint2* s = stg + (size_t)b * cap;
    if (tid < BNODES) { cnt_l[tid] = 0; degf[tid] = 1.0f; }
    __syncthreads();
    for (int i = tid; i < n; i += 512)
        atomicAdd(&cnt_l[s[i].x >> SRCBITS], 1);
    __syncthreads();
    int c = 0;
    if (tid < BNODES) { c = cnt_l[tid]; cnt_l[tid] = 0; }  // reuse as fill ctr
    int v = c;
    for (int off = 1; off < 64; off <<= 1) {
        int u = __shfl_up(v, off);
        if (lane >= off) v += u;
    }
    if (wvid < 4 && lane == 63) wsum[wvid] = v;
    __syncthreads();
    if (tid < BNODES) {
        int wpre = 0;
        for (int k = 0; k < wvid; k++) wpre += wsum[k];
        base_l[tid] = v + wpre - c;
    }
    __syncthreads();
    for (int i = tid; i < n; i += 512) {
        uint2 r = s[i];
        int dl = r.x >> SRCBITS;
        int src = (int)(r.x & ((1u << SRCBITS) - 1));
        int pos = cb + base_l[dl] + atomicAdd(&cnt_l[dl], 1);
        cv[pos] = make_int2(src, (int)r.y);
        atomicAdd(&degf[dl], __uint_as_float(r.y));
    }
    __syncthreads();
    int gid = (b << BSHIFT) + tid;
    if (tid < BNODES && gid < N) {
        rowptr[gid] = cb + base_l[tid];
        float r = rsqrtf(degf[tid]);
        dis[gid] = r;
        p[gid] = r * x[gid];
    }
}

// Quarter-wave per node: q = sum(val*p[col]); t = dis*(q+p); tp = (t, dis).
__global__ __launch_bounds__(256) void k_q(const int* __restrict__ rowptr,
                                           const int2* __restrict__ cv,
                                           const float* __restrict__ dis,
                                           const float* __restrict__ p,
                                           float2* __restrict__ tp, int N) {
    int gid = blockIdx.x * blockDim.x + threadIdx.x;
    int wid = gid >> 4;
    int sl = threadIdx.x & 15;
    if (wid >= N) return;
    int beg = rowptr[wid], end = rowptr[wid + 1];
    float s = 0.0f;
    for (int i = beg + sl; i < end; i += 16) {
        int2 pr = cv[i];
        s += __int_as_float(pr.y) * p[pr.x];
    }
    s += __shfl_xor(s, 1);
    s += __shfl_xor(s, 2);
    s += __shfl_xor(s, 4);
    s += __shfl_xor(s, 8);
    if (sl == 0) {
        float r = dis[wid];
        tp[wid] = make_float2(r * (s + p[wid]), r);
    }
}

// Half-wave per node: lanes 0-31 -> node A, 32-63 -> node B; 4 features/lane.
__global__ __launch_bounds__(256) void k_agg(const int* __restrict__ rowptr,
                                             const int2* __restrict__ cv,
                                             const float2* __restrict__ tp,
                                             const float* __restrict__ W1,
                                             const float* __restrict__ b1,
                                             uint* __restrict__ z, int N) {
    __shared__ float2 eb[4][64];       // 2 KB: per-wave, 32 slots per half
    int tid = threadIdx.x;
    int wvid = tid >> 6, lane = tid & 63;
    int half = lane >> 5, hl = lane & 31;
    int node = ((blockIdx.x * 256 + tid) >> 6) * 2 + half;
    bool valid = node < N;
    float4 w1 = valid ? *(const float4*)(W1 + hl * 4) : make_float4(0, 0, 0, 0);
    float4 bb = valid ? *(const float4*)(b1 + hl * 4) : make_float4(0, 0, 0, 0);
    int beg = 0, end = 0;
    if (valid) { beg = rowptr[node]; end = rowptr[node + 1]; }
    int nb = (end - beg + 31) >> 5;
    nb = max(nb, __shfl_xor(nb, 32));            // uniform across the wave pair
    float4 aA = make_float4(0, 0, 0, 0), aB = make_float4(0, 0, 0, 0);
    const float4* ebp = (const float4*)&eb[wvid][half * 32];
    for (int bt = 0; bt < nb; bt++) {
        int eidx = beg + bt * 32 + hl;
        float wd = 0.0f, tt = 0.0f;
        if (eidx < end) {
            int2 pr = cv[eidx];
            float2 tps = tp[pr.x];               // 8B gather, L2-resident
            wd = __int_as_float(pr.y) * tps.y;   // w_e * dis_src
            tt = tps.x;                          // t_src
        }
        eb[wvid][lane] = make_float2(wd, tt);
        int m = min(32, end - (beg + bt * 32)); if (m < 0) m = 0;
        int hm = (m + 1) >> 1;
        hm = max(hm, __shfl_xor(hm, 32));
        int u = 0;
        for (; u + 2 <= hm; u += 2) {
            float4 e2 = ebp[u];
            float4 e3 = ebp[u + 1];
            aA.x = fmaf(e2.x, fmaxf(fmaf(e2.y, w1.x, bb.x), 0.f), aA.x);
            aA.y = fmaf(e2.x, fmaxf(fmaf(e2.y, w1.y, bb.y), 0.f), aA.y);
            aA.z = fmaf(e2.x, fmaxf(fmaf(e2.y, w1.z, bb.z), 0.f), aA.z);
            aA.w = fmaf(e2.x, fmaxf(fmaf(e2.y, w1.w, bb.w), 0.f), aA.w);
            aA.x = fmaf(e2.z, fmaxf(fmaf(e2.w, w1.x, bb.x), 0.f), aA.x);
            aA.y = fmaf(e2.z, fmaxf(fmaf(e2.w, w1.y, bb.y), 0.f), aA.y);
            aA.z = fmaf(e2.z, fmaxf(fmaf(e2.w, w1.z, bb.z), 0.f), aA.z);
            aA.w = fmaf(e2.z, fmaxf(fmaf(e2.w, w1.w, bb.w), 0.f), aA.w);
            aB.x = fmaf(e3.x, fmaxf(fmaf(e3.y, w1.x, bb.x), 0.f), aB.x);
            aB.y = fmaf(e3.x, fmaxf(fmaf(e3.y, w1.y, bb.y), 0.f), aB.y);
            aB.z = fmaf(e3.x, fmaxf(fmaf(e3.y, w1.z, bb.z), 0.f), aB.z);
            aB.w = fmaf(e3.x, fmaxf(fmaf(e3.y, w1.w, bb.w), 0.f), aB.w);
            aB.x = fmaf(e3.z, fmaxf(fmaf(e3.w, w1.x, bb.x), 0.f), aB.x);
            aB.y = fmaf(e3.z, fmaxf(fmaf(e3.w, w1.y, bb.y), 0.f), aB.y);
            aB.z = fmaf(e3.z, fmaxf(fmaf(e3.w, w1.z, bb.z), 0.f), aB.z);
            aB.w = fmaf(e3.z, fmaxf(fmaf(e3.w, w1.w, bb.w), 0.f), aB.w);
        }
        if (u < hm) {
            float4 e2 = ebp[u];
            aA.x = fmaf(e2.x, fmaxf(fmaf(e2.y, w1.x, bb.x), 0.f), aA.x);
            aA.y = fmaf(e2.x, fmaxf(fmaf(e2.y, w1.y, bb.y), 0.f), aA.y);
            aA.z = fmaf(e2.x, fmaxf(fmaf(e2.y, w1.z, bb.z), 0.f), aA.z);
            aA.w = fmaf(e2.x, fmaxf(fmaf(e2.y, w1.w, bb.w), 0.f), aA.w);
            aA.x = fmaf(e2.z, fmaxf(fmaf(e2.w, w1.x, bb.x), 0.f), aA.x);
            aA.y = fmaf(e2.z, fmaxf(fmaf(e2.w, w1.y, bb.y), 0.f), aA.y);
            aA.z = fmaf(e2.z, fmaxf(fmaf(e2.w, w1.z, bb.z), 0.f), aA.z);
            aA.w = fmaf(e2.z, fmaxf(fmaf(e2.w, w1.w, bb.w), 0.f), aA.w);
        }
    }
    if (!valid) return;
    float2 tpd = tp[node];
    float rd = tpd.y;
    float o0 = rd * (aA.x + aB.x + rd * fmaxf(fmaf(tpd.x, w1.x, bb.x), 0.f));
    float o1 = rd * (aA.y + aB.y + rd * fmaxf(fmaf(tpd.x, w1.y, bb.y), 0.f));
    float o2 = rd * (aA.z + aB.z + rd * fmaxf(fmaf(tpd.x, w1.z, bb.z), 0.f));
    float o3 = rd * (aA.w + aB.w + rd * fmaxf(fmaf(tpd.x, w1.w, bb.w), 0.f));
    ((uint2*)(z + (size_t)node * 64))[hl] = make_uint2(packbf(o0, o1), packbf(o2, o3));
}

// Fused MLP v2: 16 rows/wave, 64 rows/block, grid x2 (TLP for the latency-
// bound MFMA->LDS->MFMA chain) + double-buffered st[c&1] (kills WAR serial-
// ization between a2-reads of chunk c and staging writes of chunk c+1).
__global__ __launch_bounds__(256) void k_mlp(const ushort* __restrict__ A,    // z bf16 [N][128]
                                             const ushort* __restrict__ Bt1,  // [16][256][8]
                                             const ushort* __restrict__ Bt2,  // [32][128][8]
                                             const float* __restrict__ b2,
                                             const float* __restrict__ bl1,
                                             const float* __restrict__ wl2,
                                             const float* __restrict__ bl2,
                                             float* __restrict__ out, int M) {
    __shared__ ushort st[4][2][16][40];   // per-wave, 2 parity buffers; 80B rows
    int tid = threadIdx.x;
    int wv = tid >> 6, lane = tid & 63;
    int l15 = lane & 15, quad = lane >> 4;
    int row0 = blockIdx.x * 64 + wv * 16;
    int r0 = row0 + l15; r0 = r0 < M ? r0 : M - 1;   // clamp; stores guarded

    bf8_t a1[4];                          // all A1 frags resident (16 VGPR)
    for (int kc = 0; kc < 4; kc++)
        a1[kc] = *(const bf8_t*)(A + (size_t)r0 * 128 + kc * 32 + quad * 8);
    f32x4 acc2[8];
    for (int j = 0; j < 8; j++) acc2[j] = (f32x4){0.f, 0.f, 0.f, 0.f};

    #pragma unroll
    for (int c = 0; c < 8; c++) {         // 32-col chunk of h2 == 32-k of GEMM2
        f32x4 acc1[2];
        acc1[0] = (f32x4){0.f, 0.f, 0.f, 0.f};
        acc1[1] = (f32x4){0.f, 0.f, 0.f, 0.f};
        for (int kc = 0; kc < 4; kc++)
            for (int nt = 0; nt < 2; nt++) {
                bf8_t b = *(const bf8_t*)(Bt1 +
                    ((size_t)(kc * 4 + quad) * 256 + c * 32 + nt * 16 + l15) * 8);
                acc1[nt] = __builtin_amdgcn_mfma_f32_16x16x32_bf16(a1[kc], b, acc1[nt], 0, 0, 0);
            }
        for (int nt = 0; nt < 2; nt++) {
            float bb = b2[c * 32 + nt * 16 + l15];
            for (int rg = 0; rg < 4; rg++)
                st[wv][c & 1][quad * 4 + rg][nt * 16 + l15] =
                    f2bf(fmaxf(acc1[nt][rg] + bb, 0.f));
        }
        bf8_t a2 = *(const bf8_t*)&st[wv][c & 1][l15][quad * 8];
        for (int nt2 = 0; nt2 < 8; nt2++) {
            bf8_t b = *(const bf8_t*)(Bt2 +
                ((size_t)(c * 4 + quad) * 128 + nt2 * 16 + l15) * 8);
            acc2[nt2] = __builtin_amdgcn_mfma_f32_16x16x32_bf16(a2, b, acc2[nt2], 0, 0, 0);
        }
    }
    float rs[4] = {};
    for (int nt2 = 0; nt2 < 8; nt2++) {
        int col = nt2 * 16 + l15;
        float bb = bl1[col], ww = wl2[col];
        for (int rg = 0; rg < 4; rg++)
            rs[rg] += fmaxf(acc2[nt2][rg] + bb, 0.f) * ww;
    }
    float base = bl2[0];
    for (int rg = 0; rg < 4; rg++) {
        float s = rs[rg];
        s += __shfl_xor(s, 1);
        s += __shfl_xor(s, 2);
        s += __shfl_xor(s, 4);
        s += __shfl_xor(s, 8);
        int row = row0 + quad * 4 + rg;
        if (l15 == 0 && row < M) out[row] = s + base;
    }
}

extern "C" void kernel_launch(void* const* d_in, const int* in_sizes, int n_in,
                              void* d_out, int out_size, void* d_ws, size_t ws_size,
                              hipStream_t stream) {
    const float* x   = (const float*)d_in[0];
    const int*   ei  = (const int*)d_in[1];
    const float* ew  = (const float*)d_in[2];
    const float* W1  = (const float*)d_in[3];
    const float* b1  = (const float*)d_in[4];
    const float* W2  = (const float*)d_in[5];
    const float* b2  = (const float*)d_in[6];
    const float* Wl1 = (const float*)d_in[7];
    const float* bl1 = (const float*)d_in[8];
    const float* Wl2 = (const float*)d_in[9];
    const float* bl2 = (const float*)d_in[10];
    float* out = (float*)d_out;
    const int N = in_sizes[0];
    const int E = in_sizes[2];

    const int nbuck = (N + BNODES - 1) >> BSHIFT;             // 391
    const int cap = ((((E / nbuck) * 5) / 4 + 1024) + 7) & ~7; // slack, 64B-aligned

    char* w = (char*)d_ws;
    size_t off = 0;
    auto alloc = [&](size_t bytes) -> void* {
        void* p = w + off;
        off = align256(off + bytes);
        return p;
    };
    uint*   z      = (uint*)alloc((size_t)N * 64 * 4);      // bf16 [N][128]
    float2* tp     = (float2*)alloc((size_t)N * 8);         // (t, dis)
    float*  dis    = (float*)alloc((size_t)N * 4);
    float*  p_     = (float*)alloc((size_t)N * 4);
    int*    rowptr = (int*)alloc((size_t)(N + 1) * 4);
    int2*   cv     = (int2*)alloc((size_t)E * 8);
    uint2*  stg    = (uint2*)alloc((size_t)nbuck * cap * 8);
    int*    bfill  = (int*)alloc(512 * 4);
    ushort* Bt1    = (ushort*)alloc(32768 * 2);
    ushort* Bt2    = (ushort*)alloc(32768 * 2);

    k_init<<<128, 256, 0, stream>>>(W2, Wl1, Bt1, Bt2, bfill);
    k_part<<<(E + EPB - 1) / EPB, 256, 0, stream>>>(ei, ew, bfill, stg, E, nbuck, cap);
    k_fine<<<nbuck, 512, 0, stream>>>(stg, bfill, x, dis, p_, rowptr, cv, cap, N, E, nbuck);
    k_q<<<(N * 16 + 255) / 256, 256, 0, stream>>>(rowptr, cv, dis, p_, tp, N);
    k_agg<<<(N + 7) / 8, 256, 0, stream>>>(rowptr, cv, tp, W1, b1, z, N);
    k_mlp<<<(N + 63) / 64, 256, 0, stream>>>((const ushort*)z, Bt1, Bt2,
                                             b2, bl1, Wl2, bl2, out, N);
}

// Round 8
// 196.572 us; speedup vs baseline: 1.0359x; 1.0004x over previous
//
#include <hip/hip_runtime.h>

// GCN on MI355X — round 20: k_mlp v3 — staging-machinery cut.
// Evidence: r18 counters (k_mlp 41.8us, MfmaUtil 11%, VALUBusy 23%) + r19
// null (TLP x2 = no change) => cost is the per-c staging section (16 scalar
// ds_write_b16 + addr VALU serialized between MFMA groups), not occupancy.
// v3 (back at 32 rows/wave, 782 blocks = 1x B traffic):
//  - pack (nt0,nt1) per row into uint -> 8 ds_write_b32 (half the LDS ops)
//  - GEMM2 k-order becomes lo/hi-interleaved -> compensate by k-permuting
//    Bt2 in k_init (dot is k-permutation invariant; ulp-level only)
//  - st[c&1] double-buffer + full unroll (GEMM1(c+1) overlaps GEMM2(c))
//  - row stride 20 words keeps ds_read_b128 16B-aligned; <=2-way banks
// All other kernels identical to r19/r16.

#define HD 128
#define HD2 256
#define BSHIFT 8             // 256 nodes per bucket -> 391 buckets
#define BNODES 256
#define SRCBITS 17           // N=100000 < 2^17
#define EPB 4096             // edges per k_part block

typedef __attribute__((ext_vector_type(8))) short bf8_t;   // 8 x bf16 (4 VGPR)
typedef __attribute__((ext_vector_type(4))) float f32x4;

static inline size_t align256(size_t x) { return (x + 255) & ~(size_t)255; }

__device__ inline ushort f2bf(float f) {            // RNE f32 -> bf16
    uint u = __float_as_uint(f);
    uint r = u + 0x7fffu + ((u >> 16) & 1u);
    return (ushort)(r >> 16);
}
__device__ inline uint packbf(float a, float b) {
    return (uint)f2bf(a) | ((uint)f2bf(b) << 16);
}

// prepB (weights -> bf16 chunk layout) + zero bfill. 128 blocks x 256.
// Bt2 is k-PERMUTED to match k_mlp v3's packed staging: b-frag slot j of
// chunk ck corresponds to Wl1 k-row (ck>>2)*32 + ((j&1)<<4) + (ck&3)*4 + (j>>1).
__global__ void k_init(const float* __restrict__ W2, const float* __restrict__ Wl1,
                       ushort* __restrict__ Bt1, ushort* __restrict__ Bt2,
                       int* __restrict__ bfill) {
    int o = blockIdx.x * blockDim.x + threadIdx.x;
    if (o < 512) bfill[o] = 0;
    if (o >= 32768) return;
    {   // Bt1: K=128, NCOLS=256: Bt[(k>>3)*256*8 + n*8 + (k&7)]
        int k0 = o & 7, n = (o >> 3) & 255, k8 = o >> 11;
        Bt1[o] = f2bf(W2[(size_t)(k8 * 8 + k0) * 256 + n]);
    }
    {   // Bt2: K=256, NCOLS=128, k-permuted (see above)
        int j = o & 7, n = (o >> 3) & 127, ck = o >> 10;
        int kk = (ck >> 2) * 32 + ((j & 1) << 4) + (ck & 3) * 4 + (j >> 1);
        Bt2[o] = f2bf(Wl1[(size_t)kk * 128 + n]);
    }
}

// Phase 1 v2: stream 4096 edges/block, partition into 391 dst-buckets with
// block-local grouping so global stores are contiguous runs (~84B) per bucket.
__global__ __launch_bounds__(256) void k_part(const int* __restrict__ ei,
                                              const float* __restrict__ ew,
                                              int* __restrict__ bfill,
                                              uint2* __restrict__ stg,
                                              int E, int nbuck, int cap) {
    __shared__ int lcnt[4][512];       // per-wave bucket counts -> tot in [0]
    __shared__ int lbase[4][512];      // per-wave exclusive prefix per bucket
    __shared__ int lpre[512];          // block-local exclusive bucket start
    __shared__ int delta[512];         // global_addr = delta[bkt] + loc
    __shared__ uint2 sstage[EPB];      // 32 KB staged (pack, w)
    __shared__ uint  ga[EPB];          // 16 KB precomputed global slots
    __shared__ int wscan[8];
    __shared__ int nvs;
    int tid = threadIdx.x;
    int wvid = tid >> 6, lane = tid & 63;
    for (int i = tid; i < 512; i += 256) {
        lcnt[0][i] = 0; lcnt[1][i] = 0; lcnt[2][i] = 0; lcnt[3][i] = 0;
    }
    __syncthreads();
    bool is64 = (ei[1] == 0) && (ei[3] == 0) && (ei[5] == 0) && (ei[7] == 0);
    int e0 = blockIdx.x * EPB;
    uint pack[16]; uint wb[16]; short bkt[16]; short rank[16];
    for (int u = 0; u < 16; u++) {
        int e = e0 + u * 256 + tid;
        bkt[u] = -1;
        if (e < E) {
            int s, d;
            if (is64) { s = ei[2 * e]; d = ei[2 * (E + e)]; }
            else      { s = ei[e];     d = ei[E + e]; }
            bkt[u] = (short)(d >> BSHIFT);
            pack[u] = ((uint)(d & (BNODES - 1)) << SRCBITS) | (uint)s;
            wb[u] = __float_as_uint(ew[e]);
            rank[u] = (short)atomicAdd(&lcnt[wvid][bkt[u]], 1);  // <=1024, fits
        }
    }
    __syncthreads();
    for (int i = tid; i < 512; i += 256) {
        int t0 = lcnt[0][i], t1 = lcnt[1][i], t2 = lcnt[2][i], t3 = lcnt[3][i];
        lbase[0][i] = 0; lbase[1][i] = t0;
        lbase[2][i] = t0 + t1; lbase[3][i] = t0 + t1 + t2;
        lcnt[0][i] = t0 + t1 + t2 + t3;            // tot
    }
    __syncthreads();
    // inclusive scan of tot over 512 buckets: 8 wave-segments of 64
    int inc[2];
    for (int r = 0; r < 2; r++) {
        int v = lcnt[0][r * 256 + tid];
        for (int off = 1; off < 64; off <<= 1) {
            int u = __shfl_up(v, off);
            if (lane >= off) v += u;
        }
        inc[r] = v;
        if (lane == 63) wscan[r * 4 + wvid] = v;
    }
    __syncthreads();
    if (tid == 0) {
        int run = 0;
        for (int s2 = 0; s2 < 8; s2++) { int t = wscan[s2]; wscan[s2] = run; run += t; }
        nvs = run;
    }
    __syncthreads();
    for (int r = 0; r < 2; r++) {
        int i = r * 256 + tid;
        int tot = lcnt[0][i];
        int excl = inc[r] - tot + wscan[r * 4 + wvid];
        int gb = 0;
        if (tot && i < nbuck) gb = atomicAdd(&bfill[i], tot);
        lpre[i] = excl;
        delta[i] = i * cap + gb - excl;            // < 2^31, window line-aligned
    }
    __syncthreads();
    for (int u = 0; u < 16; u++)
        if (bkt[u] >= 0) {
            int b = bkt[u];
            int loc = lpre[b] + lbase[wvid][b] + rank[u];
            sstage[loc] = make_uint2(pack[u], wb[u]);
            ga[loc] = (uint)(delta[b] + loc);
        }
    __syncthreads();
    int nv = nvs;
    for (int ch = 0; ch < 16; ch++) {              // lanes adjacent -> runs
        int loc = ch * 256 + tid;
        if (loc < nv) stg[ga[loc]] = sstage[loc];
    }
}

// Phase 2 (r16 version): one 512-thread block per 256-node bucket. Inline
// cvbase reduction -> LDS count -> scan -> ranked scatter. Fused rowptr/dis/p.
__global__ __launch_bounds__(512) void k_fine(const uint2* __restrict__ stg,
                                              const int* __restrict__ bfill,
                                              const float* __restrict__ x,
                                              float* __restrict__ dis,
                                              float* __restrict__ p,
                                              int* __restrict__ rowptr,
                                              int2* __restrict__ cv,
                                              int cap, int N, int E, int nbuck) {
    __shared__ int cnt_l[BNODES];
    __shared__ int base_l[BNODES];
    __shared__ float degf[BNODES];
    __shared__ int wsum[8];
    int b = blockIdx.x, tid = threadIdx.x;
    int lane = tid & 63, wvid = tid >> 6;
    // cvbase[b] = sum_{i<b} bfill[i] via masked block reduction
    int a = (tid < b && tid < nbuck) ? bfill[tid] : 0;   // nbuck <= 512
    for (int off = 32; off > 0; off >>= 1) a += __shfl_xor(a, off);
    if (lane == 0) wsum[wvid] = a;
    __syncthreads();
    int cb = wsum[0] + wsum[1] + wsum[2] + wsum[3] +
             wsum[4] + wsum[5] + wsum[6] + wsum[7];
    int n = bfill[b];
    if (b == nbuck - 1 && tid == 0) rowptr[N] = E;
    const uint2* s = stg + (size_t)b * cap;
    if (tid < BNODES) { cnt_l[tid] = 0; degf[tid] = 1.0f; }
    __syncthreads();
    for (int i = tid; i < n; i += 512)
        atomicAdd(&cnt_l[s[i].x >> SRCBITS], 1);
    __syncthreads();
    int c = 0;
    if (tid < BNODES) { c = cnt_l[tid]; cnt_l[tid] = 0; }  // reuse as fill ctr
    int v = c;
    for (int off = 1; off < 64; off <<= 1) {
        int u = __shfl_up(v, off);
        if (lane >= off) v += u;
    }
    if (wvid < 4 && lane == 63) wsum[wvid] = v;
    __syncthreads();
    if (tid < BNODES) {
        int wpre = 0;
        for (int k = 0; k < wvid; k++) wpre += wsum[k];
        base_l[tid] = v + wpre - c;
    }
    __syncthreads();
    for (int i = tid; i < n; i += 512) {
        uint2 r = s[i];
        int dl = r.x >> SRCBITS;
        int src = (int)(r.x & ((1u << SRCBITS) - 1));
        int pos = cb + base_l[dl] + atomicAdd(&cnt_l[dl], 1);
        cv[pos] = make_int2(src, (int)r.y);
        atomicAdd(&degf[dl], __uint_as_float(r.y));
    }
    __syncthreads();
    int gid = (b << BSHIFT) + tid;
    if (tid < BNODES && gid < N) {
        rowptr[gid] = cb + base_l[tid];
        float r = rsqrtf(degf[tid]);
        dis[gid] = r;
        p[gid] = r * x[gid];
    }
}

// Quarter-wave per node: q = sum(val*p[col]); t = dis*(q+p); tp = (t, dis).
__global__ __launch_bounds__(256) void k_q(const int* __restrict__ rowptr,
                                           const int2* __restrict__ cv,
                                           const float* __restrict__ dis,
                                           const float* __restrict__ p,
                                           float2* __restrict__ tp, int N) {
    int gid = blockIdx.x * blockDim.x + threadIdx.x;
    int wid = gid >> 4;
    int sl = threadIdx.x & 15;
    if (wid >= N) return;
    int beg = rowptr[wid], end = rowptr[wid + 1];
    float s = 0.0f;
    for (int i = beg + sl; i < end; i += 16) {
        int2 pr = cv[i];
        s += __int_as_float(pr.y) * p[pr.x];
    }
    s += __shfl_xor(s, 1);
    s += __shfl_xor(s, 2);
    s += __shfl_xor(s, 4);
    s += __shfl_xor(s, 8);
    if (sl == 0) {
        float r = dis[wid];
        tp[wid] = make_float2(r * (s + p[wid]), r);
    }
}

// Half-wave per node: lanes 0-31 -> node A, 32-63 -> node B; 4 features/lane.
__global__ __launch_bounds__(256) void k_agg(const int* __restrict__ rowptr,
                                             const int2* __restrict__ cv,
                                             const float2* __restrict__ tp,
                                             const float* __restrict__ W1,
                                             const float* __restrict__ b1,
                                             uint* __restrict__ z, int N) {
    __shared__ float2 eb[4][64];       // 2 KB: per-wave, 32 slots per half
    int tid = threadIdx.x;
    int wvid = tid >> 6, lane = tid & 63;
    int half = lane >> 5, hl = lane & 31;
    int node = ((blockIdx.x * 256 + tid) >> 6) * 2 + half;
    bool valid = node < N;
    float4 w1 = valid ? *(const float4*)(W1 + hl * 4) : make_float4(0, 0, 0, 0);
    float4 bb = valid ? *(const float4*)(b1 + hl * 4) : make_float4(0, 0, 0, 0);
    int beg = 0, end = 0;
    if (valid) { beg = rowptr[node]; end = rowptr[node + 1]; }
    int nb = (end - beg + 31) >> 5;
    nb = max(nb, __shfl_xor(nb, 32));            // uniform across the wave pair
    float4 aA = make_float4(0, 0, 0, 0), aB = make_float4(0, 0, 0, 0);
    const float4* ebp = (const float4*)&eb[wvid][half * 32];
    for (int bt = 0; bt < nb; bt++) {
        int eidx = beg + bt * 32 + hl;
        float wd = 0.0f, tt = 0.0f;
        if (eidx < end) {
            int2 pr = cv[eidx];
            float2 tps = tp[pr.x];               // 8B gather, L2-resident
            wd = __int_as_float(pr.y) * tps.y;   // w_e * dis_src
            tt = tps.x;                          // t_src
        }
        eb[wvid][lane] = make_float2(wd, tt);
        int m = min(32, end - (beg + bt * 32)); if (m < 0) m = 0;
        int hm = (m + 1) >> 1;
        hm = max(hm, __shfl_xor(hm, 32));
        int u = 0;
        for (; u + 2 <= hm; u += 2) {
            float4 e2 = ebp[u];
            float4 e3 = ebp[u + 1];
            aA.x = fmaf(e2.x, fmaxf(fmaf(e2.y, w1.x, bb.x), 0.f), aA.x);
            aA.y = fmaf(e2.x, fmaxf(fmaf(e2.y, w1.y, bb.y), 0.f), aA.y);
            aA.z = fmaf(e2.x, fmaxf(fmaf(e2.y, w1.z, bb.z), 0.f), aA.z);
            aA.w = fmaf(e2.x, fmaxf(fmaf(e2.y, w1.w, bb.w), 0.f), aA.w);
            aA.x = fmaf(e2.z, fmaxf(fmaf(e2.w, w1.x, bb.x), 0.f), aA.x);
            aA.y = fmaf(e2.z, fmaxf(fmaf(e2.w, w1.y, bb.y), 0.f), aA.y);
            aA.z = fmaf(e2.z, fmaxf(fmaf(e2.w, w1.z, bb.z), 0.f), aA.z);
            aA.w = fmaf(e2.z, fmaxf(fmaf(e2.w, w1.w, bb.w), 0.f), aA.w);
            aB.x = fmaf(e3.x, fmaxf(fmaf(e3.y, w1.x, bb.x), 0.f), aB.x);
            aB.y = fmaf(e3.x, fmaxf(fmaf(e3.y, w1.y, bb.y), 0.f), aB.y);
            aB.z = fmaf(e3.x, fmaxf(fmaf(e3.y, w1.z, bb.z), 0.f), aB.z);
            aB.w = fmaf(e3.x, fmaxf(fmaf(e3.y, w1.w, bb.w), 0.f), aB.w);
            aB.x = fmaf(e3.z, fmaxf(fmaf(e3.w, w1.x, bb.x), 0.f), aB.x);
            aB.y = fmaf(e3.z, fmaxf(fmaf(e3.w, w1.y, bb.y), 0.f), aB.y);
            aB.z = fmaf(e3.z, fmaxf(fmaf(e3.w, w1.z, bb.z), 0.f), aB.z);
            aB.w = fmaf(e3.z, fmaxf(fmaf(e3.w, w1.w, bb.w), 0.f), aB.w);
        }
        if (u < hm) {
            float4 e2 = ebp[u];
            aA.x = fmaf(e2.x, fmaxf(fmaf(e2.y, w1.x, bb.x), 0.f), aA.x);
            aA.y = fmaf(e2.x, fmaxf(fmaf(e2.y, w1.y, bb.y), 0.f), aA.y);
            aA.z = fmaf(e2.x, fmaxf(fmaf(e2.y, w1.z, bb.z), 0.f), aA.z);
            aA.w = fmaf(e2.x, fmaxf(fmaf(e2.y, w1.w, bb.w), 0.f), aA.w);
            aA.x = fmaf(e2.z, fmaxf(fmaf(e2.w, w1.x, bb.x), 0.f), aA.x);
            aA.y = fmaf(e2.z, fmaxf(fmaf(e2.w, w1.y, bb.y), 0.f), aA.y);
            aA.z = fmaf(e2.z, fmaxf(fmaf(e2.w, w1.z, bb.z), 0.f), aA.z);
            aA.w = fmaf(e2.z, fmaxf(fmaf(e2.w, w1.w, bb.w), 0.f), aA.w);
        }
    }
    if (!valid) return;
    float2 tpd = tp[node];
    float rd = tpd.y;
    float o0 = rd * (aA.x + aB.x + rd * fmaxf(fmaf(tpd.x, w1.x, bb.x), 0.f));
    float o1 = rd * (aA.y + aB.y + rd * fmaxf(fmaf(tpd.x, w1.y, bb.y), 0.f));
    float o2 = rd * (aA.z + aB.z + rd * fmaxf(fmaf(tpd.x, w1.z, bb.z), 0.f));
    float o3 = rd * (aA.w + aB.w + rd * fmaxf(fmaf(tpd.x, w1.w, bb.w), 0.f));
    ((uint2*)(z + (size_t)node * 64))[hl] = make_uint2(packbf(o0, o1), packbf(o2, o3));
}

// Fused MLP v3: 32 rows/wave, b32-packed double-buffered staging.
// Staging: st32[row][l15] = pack(h2[row][l15], h2[row][16+l15]).
// a2 b128 read at [mt*16+l15][quad*4] delivers k-order (q4+w interleaved with
// 16+q4+w) -> matched by k-permuted Bt2 (see k_init).
__global__ __launch_bounds__(256) void k_mlp(const ushort* __restrict__ A,    // z bf16 [N][128]
                                             const ushort* __restrict__ Bt1,  // [16][256][8]
                                             const ushort* __restrict__ Bt2,  // [32][128][8] k-perm
                                             const float* __restrict__ b2,
                                             const float* __restrict__ bl1,
                                             const float* __restrict__ wl2,
                                             const float* __restrict__ bl2,
                                             float* __restrict__ out, int M) {
    __shared__ uint st[4][2][32][20];  // 20KB: per-wave dbuf; 80B row stride
    int tid = threadIdx.x;
    int wv = tid >> 6, lane = tid & 63;
    int l15 = lane & 15, quad = lane >> 4;
    int row0 = blockIdx.x * 128 + wv * 32;
    int r0 = row0 + l15;      r0 = r0 < M ? r0 : M - 1;   // clamp; stores guarded
    int r1 = row0 + 16 + l15; r1 = r1 < M ? r1 : M - 1;

    bf8_t a1[2][4];                       // all A1 frags resident (32 VGPR)
    for (int kc = 0; kc < 4; kc++) {
        a1[0][kc] = *(const bf8_t*)(A + (size_t)r0 * 128 + kc * 32 + quad * 8);
        a1[1][kc] = *(const bf8_t*)(A + (size_t)r1 * 128 + kc * 32 + quad * 8);
    }
    f32x4 acc2[2][8];
    for (int i = 0; i < 2; i++)
        for (int j = 0; j < 8; j++) acc2[i][j] = (f32x4){0.f, 0.f, 0.f, 0.f};

    #pragma unroll
    for (int c = 0; c < 8; c++) {         // 32-col chunk of h2 == 32-k of GEMM2
        f32x4 acc1[2][2];
        for (int i = 0; i < 2; i++)
            for (int j = 0; j < 2; j++) acc1[i][j] = (f32x4){0.f, 0.f, 0.f, 0.f};
        for (int kc = 0; kc < 4; kc++)
            for (int nt = 0; nt < 2; nt++) {
                bf8_t b = *(const bf8_t*)(Bt1 +
                    ((size_t)(kc * 4 + quad) * 256 + c * 32 + nt * 16 + l15) * 8);
                acc1[0][nt] = __builtin_amdgcn_mfma_f32_16x16x32_bf16(a1[0][kc], b, acc1[0][nt], 0, 0, 0);
                acc1[1][nt] = __builtin_amdgcn_mfma_f32_16x16x32_bf16(a1[1][kc], b, acc1[1][nt], 0, 0, 0);
            }
        float bb0 = b2[c * 32 + l15];
        float bb1 = b2[c * 32 + 16 + l15];
        for (int mt = 0; mt < 2; mt++)
            for (int rg = 0; rg < 4; rg++)
                st[wv][c & 1][mt * 16 + quad * 4 + rg][l15] =
                    packbf(fmaxf(acc1[mt][0][rg] + bb0, 0.f),
                           fmaxf(acc1[mt][1][rg] + bb1, 0.f));
        bf8_t a2_0 = *(const bf8_t*)&st[wv][c & 1][l15][quad * 4];
        bf8_t a2_1 = *(const bf8_t*)&st[wv][c & 1][16 + l15][quad * 4];
        for (int nt2 = 0; nt2 < 8; nt2++) {
            bf8_t b = *(const bf8_t*)(Bt2 +
                ((size_t)(c * 4 + quad) * 128 + nt2 * 16 + l15) * 8);
            acc2[0][nt2] = __builtin_amdgcn_mfma_f32_16x16x32_bf16(a2_0, b, acc2[0][nt2], 0, 0, 0);
            acc2[1][nt2] = __builtin_amdgcn_mfma_f32_16x16x32_bf16(a2_1, b, acc2[1][nt2], 0, 0, 0);
        }
    }
    float rs[2][4] = {};
    for (int nt2 = 0; nt2 < 8; nt2++) {
        int col = nt2 * 16 + l15;
        float bb = bl1[col], ww = wl2[col];
        for (int mt = 0; mt < 2; mt++)
            for (int rg = 0; rg < 4; rg++)
                rs[mt][rg] += fmaxf(acc2[mt][nt2][rg] + bb, 0.f) * ww;
    }
    float base = bl2[0];
    for (int mt = 0; mt < 2; mt++)
        for (int rg = 0; rg < 4; rg++) {
            float s = rs[mt][rg];
            s += __shfl_xor(s, 1);
            s += __shfl_xor(s, 2);
            s += __shfl_xor(s, 4);
            s += __shfl_xor(s, 8);
            int row = row0 + mt * 16 + quad * 4 + rg;
            if (l15 == 0 && row < M) out[row] = s + base;
        }
}

extern "C" void kernel_launch(void* const* d_in, const int* in_sizes, int n_in,
                              void* d_out, int out_size, void* d_ws, size_t ws_size,
                              hipStream_t stream) {
    const float* x   = (const float*)d_in[0];
    const int*   ei  = (const int*)d_in[1];
    const float* ew  = (const float*)d_in[2];
    const float* W1  = (const float*)d_in[3];
    const float* b1  = (const float*)d_in[4];
    const float* W2  = (const float*)d_in[5];
    const float* b2  = (const float*)d_in[6];
    const float* Wl1 = (const float*)d_in[7];
    const float* bl1 = (const float*)d_in[8];
    const float* Wl2 = (const float*)d_in[9];
    const float* bl2 = (const float*)d_in[10];
    float* out = (float*)d_out;
    const int N = in_sizes[0];
    const int E = in_sizes[2];

    const int nbuck = (N + BNODES - 1) >> BSHIFT;             // 391
    const int cap = ((((E / nbuck) * 5) / 4 + 1024) + 7) & ~7; // slack, 64B-aligned

    char* w = (char*)d_ws;
    size_t off = 0;
    auto alloc = [&](size_t bytes) -> void* {
        void* p = w + off;
        off = align256(off + bytes);
        return p;
    };
    uint*   z      = (uint*)alloc((size_t)N * 64 * 4);      // bf16 [N][128]
    float2* tp     = (float2*)alloc((size_t)N * 8);         // (t, dis)
    float*  dis    = (float*)alloc((size_t)N * 4);
    float*  p_     = (float*)alloc((size_t)N * 4);
    int*    rowptr = (int*)alloc((size_t)(N + 1) * 4);
    int2*   cv     = (int2*)alloc((size_t)E * 8);
    uint2*  stg    = (uint2*)alloc((size_t)nbuck * cap * 8);
    int*    bfill  = (int*)alloc(512 * 4);
    ushort* Bt1    = (ushort*)alloc(32768 * 2);
    ushort* Bt2    = (ushort*)alloc(32768 * 2);

    k_init<<<128, 256, 0, stream>>>(W2, Wl1, Bt1, Bt2, bfill);
    k_part<<<(E + EPB - 1) / EPB, 256, 0, stream>>>(ei, ew, bfill, stg, E, nbuck, cap);
    k_fine<<<nbuck, 512, 0, stream>>>(stg, bfill, x, dis, p_, rowptr, cv, cap, N, E, nbuck);
    k_q<<<(N * 16 + 255) / 256, 256, 0, stream>>>(rowptr, cv, dis, p_, tp, N);
    k_agg<<<(N + 7) / 8, 256, 0, stream>>>(rowptr, cv, tp, W1, b1, z, N);
    k_mlp<<<(N + 127) / 128, 256, 0, stream>>>((const ushort*)z, Bt1, Bt2,
                                               b2, bl1, Wl2, bl2, out, N);
}